// Round 4
// baseline (53.604 us; speedup 1.0000x reference)
//
#include <hip/hip_runtime.h>

// RoiAlign on FPN pyramid.
// Output: (1, N, 14, 14, 256) fp32.  N = 512 in the bench.
// R3 (= R2 with compile fix): 4 positions per wave (16 in-flight float4 loads)
//     + nontemporal output stores via native ext_vector type
//     + XCD-aware bijective block swizzle (box-contiguous chunks per XCD L2).
// Block = 256 threads = 4 waves; wave handles four (box,y,x) positions;
// lane handles 4 channels (float4). 16 positions/block -> 13 blocks/box.

#define CROP 14
#define POS (CROP * CROP)        // 196
#define C 256
#define CANON 224.0f
#define EPSF 1e-7f
#define PPW 4                    // positions per wave
#define BLK_PER_BOX 13           // ceil(196 / 16)

typedef float vfloat4 __attribute__((ext_vector_type(4)));

__global__ __launch_bounds__(256) void roi_align_kernel(
    const int* __restrict__ image_shape,
    const float* __restrict__ boxes,
    const float* __restrict__ f0,
    const float* __restrict__ f1,
    const float* __restrict__ f2,
    const float* __restrict__ f3,
    const float* __restrict__ f4,
    float* __restrict__ out)
{
    // ---- bijective XCD swizzle: hw xcd = blockIdx.x % 8; give each XCD a
    // contiguous chunk of logical blocks so one box's blocks share one L2.
    const int nwg = gridDim.x;
    const int q = nwg >> 3, r = nwg & 7;
    const int xcd = blockIdx.x & 7, slot = blockIdx.x >> 3;
    const int blk = (xcd < r ? xcd * (q + 1) : r * (q + 1) + (xcd - r) * q) + slot;

    const int box      = blk / BLK_PER_BOX;
    const int blkInBox = blk % BLK_PER_BOX;
    const int wave = threadIdx.x >> 6;
    const int lane = threadIdx.x & 63;
    const int pbase = (blkInBox * 4 + wave) * PPW;   // 0..204

    const float imgh = (float)image_shape[1];
    const float imgw = (float)image_shape[2];

    const float bx1 = boxes[box * 4 + 0];
    const float by1 = boxes[box * 4 + 1];
    const float bx2 = boxes[box * 4 + 2];
    const float by2 = boxes[box * 4 + 3];

    // level selection (reference: floor(1 + log2(sqrt(w*h)/224 + eps)), clip [0,4])
    const float w  = bx2 - bx1;
    const float h  = by2 - by1;
    const float sz = sqrtf(w * h);
    float lvf = floorf(1.0f + log2f(sz / CANON + EPSF));
    lvf = fminf(fmaxf(lvf, 0.0f), 4.0f);
    const int lv = (int)lvf;

    const int   s  = 256 >> lv;
    const float fh = (float)s;
    const float fw = (float)s;

    // normalized box, columns [y1', x1', y2', x2'] per reference
    const float ny1 = by1 / imgh * fh / (fh - 1.0f);
    const float nx1 = bx1 / imgw * fw / (fw - 1.0f);
    const float ny2 = (by2 / imgh * fh - 1.0f) / (fh - 1.0f);
    const float nx2 = (bx2 / imgw * fw - 1.0f) / (fw - 1.0f);

    const float* __restrict__ f =
        (lv == 0) ? f0 : (lv == 1) ? f1 : (lv == 2) ? f2 : (lv == 3) ? f3 : f4;

    const int cbase = lane * 4;  // 4 channels per lane

    // ---- per-position sampling parameters (fully unrolled -> registers)
    float  fxs[PPW], fys[PPW];
    bool   vv[PPW], act[PPW];
    size_t oTL[PPW], oTR[PPW], oBL[PPW], oBR[PPW];

    #pragma unroll
    for (int k = 0; k < PPW; ++k) {
        const int p  = pbase + k;
        act[k] = (p < POS);
        const int py = p / CROP;
        const int px = p % CROP;
        const float ty = (float)py / (float)(CROP - 1);
        const float tx = (float)px / (float)(CROP - 1);
        const float yc = (ny1 * (1.0f - ty) + ny2 * ty) * (fh - 1.0f);
        const float xc = (nx1 * (1.0f - tx) + nx2 * tx) * (fw - 1.0f);

        const float ylo = floorf(yc);
        fys[k] = yc - ylo;
        const int y0  = (int)fminf(fmaxf(ylo,        0.0f), fh - 1.0f);
        const int y1i = (int)fminf(fmaxf(ylo + 1.0f, 0.0f), fh - 1.0f);
        const bool vy = (yc >= 0.0f) && (yc <= fh - 1.0f);

        const float xlo = floorf(xc);
        fxs[k] = xc - xlo;
        const int x0  = (int)fminf(fmaxf(xlo,        0.0f), fw - 1.0f);
        const int x1i = (int)fminf(fmaxf(xlo + 1.0f, 0.0f), fw - 1.0f);
        const bool vx = (xc >= 0.0f) && (xc <= fw - 1.0f);

        vv[k] = vy && vx;
        oTL[k] = ((size_t)y0  * s + x0 ) * C + cbase;
        oTR[k] = ((size_t)y0  * s + x1i) * C + cbase;
        oBL[k] = ((size_t)y1i * s + x0 ) * C + cbase;
        oBR[k] = ((size_t)y1i * s + x1i) * C + cbase;
    }

    // ---- issue all 16 loads (guarded)
    vfloat4 rTL[PPW], rTR[PPW], rBL[PPW], rBR[PPW];
    #pragma unroll
    for (int k = 0; k < PPW; ++k) {
        if (act[k]) {
            rTL[k] = *(const vfloat4*)(f + oTL[k]);
            rTR[k] = *(const vfloat4*)(f + oTR[k]);
            rBL[k] = *(const vfloat4*)(f + oBL[k]);
            rBR[k] = *(const vfloat4*)(f + oBR[k]);
        }
    }

    // ---- combine + nontemporal store
    #pragma unroll
    for (int k = 0; k < PPW; ++k) {
        if (act[k]) {
            vfloat4 o;
            if (vv[k]) {
                const float fx = fxs[k], fy = fys[k];
                vfloat4 top = rTL[k] + (rTR[k] - rTL[k]) * fx;
                vfloat4 bot = rBL[k] + (rBR[k] - rBL[k]) * fx;
                o = top + (bot - top) * fy;
            } else { o = (vfloat4)0.0f; }
            vfloat4* dst = (vfloat4*)(out + ((size_t)box * POS + (pbase + k)) * C + cbase);
            __builtin_nontemporal_store(o, dst);
        }
    }
}

extern "C" void kernel_launch(void* const* d_in, const int* in_sizes, int n_in,
                              void* d_out, int out_size, void* d_ws, size_t ws_size,
                              hipStream_t stream) {
    const int*   image_shape = (const int*)d_in[0];
    const float* boxes       = (const float*)d_in[1];
    // d_in[2] = scores (unused by the reference output)
    const float* f0 = (const float*)d_in[3];
    const float* f1 = (const float*)d_in[4];
    const float* f2 = (const float*)d_in[5];
    const float* f3 = (const float*)d_in[6];
    const float* f4 = (const float*)d_in[7];
    float* out = (float*)d_out;

    const int N = in_sizes[1] / 4;  // boxes: (1, N, 4)

    dim3 grid(N * BLK_PER_BOX);
    dim3 block(256);
    roi_align_kernel<<<grid, block, 0, stream>>>(
        image_shape, boxes, f0, f1, f2, f3, f4, out);
}